// Round 6
// baseline (197.628 us; speedup 1.0000x reference)
//
#include <hip/hip_runtime.h>

#define N_NODES 100000
#define N_EDGES 1600000
#define D 64
#define CAP 32         // slot cap per node; Poisson(16): P(deg>32)~1e-5/node, ovf backstops
#define OVF_CAP 8192   // overflow edge list (backstop)
#define N_TILES 1563   // (N_NODES + 63) / 64
#define NR 8           // (legacy fill) region groups
#define SLICE_EDGES 2048
#define N_SLICES 782   // ceil(N_EDGES / SLICE_EDGES)
#define R1_BLOCKS 64   // stage-1 reduce blocks
#define R1_ROWS 25     // ceil(N_TILES / R1_BLOCKS)
#define ASTRIDE 136    // final LDS row stride in bf16 elems (128 + 8 pad)

// Bucketed partition (R12-proven) + CSR fill (R11-proven, 128-node buckets)
#define NB2 782        // buckets of 128 nodes (dst>>7)
#define BCAP2 2560     // per-bucket capacity (mean 2048, sigma~45 -> +11 sigma)
#define EPB 8192       // edges per partition block
#define P1_BLOCKS 196  // ceil(N_EDGES / EPB)
#define CVT_BLOCKS 128 // rider blocks: emb->fp8, feat->bf16, W->bf16

typedef int    vint4  __attribute__((ext_vector_type(4)));
typedef short  s16x4  __attribute__((ext_vector_type(4)));
typedef short  s16x8  __attribute__((ext_vector_type(8)));
typedef float  f32x2  __attribute__((ext_vector_type(2)));
typedef float  f32x4  __attribute__((ext_vector_type(4)));
typedef __bf16 bf16x8 __attribute__((ext_vector_type(8)));  // MFMA operand type

// f32 -> bf16 (RNE). Inputs are finite; NaN path not needed.
__device__ inline short f2bf(float f) {
    unsigned u = __builtin_bit_cast(unsigned, f);
    u += 0x7fffu + ((u >> 16) & 1u);
    return (short)(u >> 16);
}
__device__ inline s16x4 f2bf4(float4 v) {
    s16x4 r; r.x = f2bf(v.x); r.y = f2bf(v.y); r.z = f2bf(v.z); r.w = f2bf(v.w);
    return r;
}
__device__ inline float bf2f(short s) {
    return __builtin_bit_cast(float, ((unsigned)(unsigned short)s) << 16);
}

// ws layout (bytes), top tier:
//   cnt    @ 0        : N_NODES int           (0.4 MB)
//   slots  @ 401408   : N_NODES*CAP int       (12.8 MB)
//   acc16  @ 13201408 : N_NODES*D bf16        (12.8 MB) [bkt 8MB aliased pre-gather]
//   feat16 @ 26001408 : N_NODES*D bf16        (12.8 MB)
//   ovfc   @ 38801408 : int
//   ovf    @ 38801424 : OVF_CAP int2
//   part   @ 38867200 : N_TILES*64 float      (0.4 MB)  [bcnt aliased pre-final]
//   part2  @ 39267328 : R1_BLOCKS*64 float    (16 KB)
//   emb8   @ 39283712 : N_NODES*D bytes       (6.4 MB, OCP e4m3)
//   w16    @ 45683712 : 64*128 bf16           (16 KB)   [o][W1(0..63)|W2(64..127)]
#define WS_SLOTS_OFF  401408
#define WS_ACC_OFF    13201408   // mid-tier f32 acc lives here too (25.6 MB)
#define WS_ACC16_OFF  13201408
#define WS_FEAT16_OFF 26001408
#define WS_OVFC_OFF   38801408
#define WS_OVF_OFF    38801424
#define WS_PART_OFF   38867200
#define WS_PART2_OFF  39267328
#define WS_EMB8_OFF   39283712
#define WS_W16_OFF    45683712
#define WS_NEEDED     (WS_PART2_OFF + R1_BLOCKS * 64 * 4)
#define WS_NEEDED16   (WS_W16_OFF + 64 * 128 * 2)

// ---------------------------------------------------------------------------
// R12-proven pass 1: edge partition into 782 dst-buckets (128 nodes each).
// Read 8192 edges once -> LDS histogram -> 1024-wide ping-pong scan ->
// LDS-cursor scatter (+bid) -> one global atomicAdd per (block,bucket) ->
// one-thread-per-edge coalesced copy out. pk = (src<<7)|(dst&127).
// Rider blocks (>= P1_BLOCKS) convert emb->fp8 (HW cvt_pk_fp8), feat->bf16,
// and W1/W2->bf16 — read-heavy work hidden under the LDS-bound edge blocks,
// so final16's staging becomes pure bf16 copies (R15).
// ---------------------------------------------------------------------------
__global__ __launch_bounds__(512) void part_kernel(
    const int* __restrict__ edge_src, const int* __restrict__ edge_dst,
    int* __restrict__ bcnt, int* __restrict__ bkt,
    int* __restrict__ ovf_cnt, int2* __restrict__ ovf,
    const float* __restrict__ emb, unsigned* __restrict__ emb8,
    const float* __restrict__ feat, short* __restrict__ feat16,
    const float* __restrict__ W1, const float* __restrict__ W2,
    short* __restrict__ w16) {
    const int tid = threadIdx.x;
    if (blockIdx.x >= P1_BLOCKS) {
        const int rid = blockIdx.x - P1_BLOCKS;
        // emb f32 -> OCP e4m3 (HW packed cvt), 4 elems/dword.
        {
            const float4* e4 = (const float4*)emb;
            for (unsigned j = rid * 512 + tid; j < (unsigned)(N_NODES * D / 4);
                 j += CVT_BLOCKS * 512) {
                float4 v = e4[j];
                int w = 0;
                w = __builtin_amdgcn_cvt_pk_fp8_f32(v.x, v.y, w, false);
                w = __builtin_amdgcn_cvt_pk_fp8_f32(v.z, v.w, w, true);
                emb8[j] = (unsigned)w;
            }
        }
        // feat f32 -> bf16, 8 elems per s16x8 store.
        {
            const float4* f4 = (const float4*)feat;
            for (unsigned k = rid * 512 + tid; k < (unsigned)(N_NODES * D / 8);
                 k += CVT_BLOCKS * 512) {
                float4 a = f4[k * 2];
                float4 b = f4[k * 2 + 1];
                s16x4 lo = f2bf4(a), hi = f2bf4(b);
                s16x8 pk = {lo.x, lo.y, lo.z, lo.w, hi.x, hi.y, hi.z, hi.w};
                *(s16x8*)&feat16[k * 8] = pk;
            }
        }
        // W1|W2 -> bf16 in final's W_s layout (row o: W1 cols 0-63, W2 64-127).
        if (rid == 0) {
            const float4* W1v = (const float4*)W1;
            const float4* W2v = (const float4*)W2;
            for (int k = tid; k < 64 * 16; k += 512) {  // 1024 s16x8 chunks
                const int row = k >> 4, c = k & 15;
                const float4 a = (c < 8) ? W1v[row * 16 + c * 2]
                                         : W2v[row * 16 + (c - 8) * 2];
                const float4 b = (c < 8) ? W1v[row * 16 + c * 2 + 1]
                                         : W2v[row * 16 + (c - 8) * 2 + 1];
                s16x4 lo = f2bf4(a), hi = f2bf4(b);
                s16x8 pk = {lo.x, lo.y, lo.z, lo.w, hi.x, hi.y, hi.z, hi.w};
                *(s16x8*)&w16[row * 128 + c * 8] = pk;
            }
        }
        return;
    }

    __shared__ int stage[EPB];
    __shared__ unsigned short bid[EPB];
    __shared__ int scA[1024];
    __shared__ int scB[1024];
    __shared__ int hist[NB2];
    int* const cur   = scB;   // dead after scan
    int* const gbase = scA;   // dead after tot/cur captured

    const int e0 = blockIdx.x * EPB;
    for (int i = tid; i < NB2; i += 512) hist[i] = 0;
    __syncthreads();

    int ss[16], dd[16];
#pragma unroll
    for (int i = 0; i < 16; ++i) {
        const int e = e0 + i * 512 + tid;
        if (e < N_EDGES) { ss[i] = edge_src[e]; dd[i] = edge_dst[e]; }
        else             { ss[i] = 0; dd[i] = -1; }
    }

#pragma unroll
    for (int i = 0; i < 16; ++i)
        if (dd[i] >= 0) atomicAdd(&hist[dd[i] >> 7], 1);
    __syncthreads();

    scA[tid]       = (tid < NB2) ? hist[tid] : 0;
    scA[tid + 512] = 0;
    if (tid + 512 < NB2) scA[tid + 512] = hist[tid + 512];
    __syncthreads();
    {
        int* sA = scA;
        int* sB = scB;
        for (int off = 1; off < 1024; off <<= 1) {
            const int i1 = tid + 512;
            const int v0 = sA[tid] + ((tid >= off) ? sA[tid - off] : 0);
            const int v1 = sA[i1] + sA[i1 - off];
            sB[tid] = v0; sB[i1] = v1;
            __syncthreads();
            int* t = sA; sA = sB; sB = t;
        }
    }
    const int tot = scA[NB2 - 1];
    for (int i = tid; i < NB2; i += 512) cur[i] = scA[i] - hist[i];
    __syncthreads();

#pragma unroll
    for (int i = 0; i < 16; ++i) {
        if (dd[i] >= 0) {
            const int b = dd[i] >> 7;
            const int pos = atomicAdd(&cur[b], 1);
            stage[pos] = (ss[i] << 7) | (dd[i] & 127);
            bid[pos] = (unsigned short)b;
        }
    }
    for (int i = tid; i < NB2; i += 512)
        gbase[i] = atomicAdd(&bcnt[i], hist[i]);
    __syncthreads();

    for (int j = tid; j < tot; j += 512) {
        const int pk = stage[j];
        const int b  = bid[j];
        const int gpos = gbase[b] + (j - (cur[b] - hist[b]));
        if (gpos < BCAP2) {
            bkt[b * BCAP2 + gpos] = pk;
        } else {
            int oj = atomicAdd(ovf_cnt, 1);
            if (oj < OVF_CAP) ovf[oj] = make_int2(pk >> 7, (b << 7) | (pk & 127));
        }
    }
}

// ---------------------------------------------------------------------------
// R11-proven pass 2 (128-node buckets): owned CSR fill. Per-node cursors in
// LDS via int atomicAdd on a DIRECT __shared__ array (ds_add_rtn_u32 fast
// path — R3's disaster was float no-return atomics through a generic ptr).
// ---------------------------------------------------------------------------
__global__ __launch_bounds__(512) void fill2_kernel(
    const int* __restrict__ bcnt, const int* __restrict__ bkt,
    int* __restrict__ cnt, int* __restrict__ slots,
    int* __restrict__ ovf_cnt, int2* __restrict__ ovf) {
    __shared__ int lcnt[128];
    const int b = blockIdx.x;
    const int tid = threadIdx.x;
    if (tid < 128) lcnt[tid] = 0;
    __syncthreads();
    int n = bcnt[b];
    if (n > BCAP2) n = BCAP2;
    for (int i = tid; i < n; i += 512) {
        const int pk = bkt[b * BCAP2 + i];
        const int dl = pk & 127;
        const int pos = atomicAdd(&lcnt[dl], 1);   // LDS int atomic (fast path)
        const int v = (b << 7) | dl;
        if (pos < CAP) {
            slots[v * CAP + pos] = pk >> 7;
        } else {
            int j = atomicAdd(ovf_cnt, 1);
            if (j < OVF_CAP) ovf[j] = make_int2(pk >> 7, v);
        }
    }
    __syncthreads();
    if (tid < 128) {
        const int v = (b << 7) | tid;
        if (v < N_NODES) cnt[v] = lcnt[tid];
    }
}

// ---------------------------------------------------------------------------
// R14-proven gather, R15: writes acc16 (bf16) — halves gather WRITE and
// final's acc read. One wave per node; HW fp8 decode (2 cvt_pk per dword);
// 8 edges/iter (2 loads in flight per lane). Byte 0x00 decodes to +0.0 so
// masked lanes accumulate unconditionally.
// ---------------------------------------------------------------------------
__global__ __launch_bounds__(256) void gather8_kernel(
    const unsigned* __restrict__ emb8, const int* __restrict__ cnt,
    const int* __restrict__ slots, short* __restrict__ acc16) {
    const int lane = threadIdx.x & 63;
    const int wave = threadIdx.x >> 6;
    const int v = blockIdx.x * 4 + wave;
    const int q = lane >> 4;
    const int c = lane & 15;
    int deg = cnt[v];
    if (deg > CAP) deg = CAP;
    const int si = slots[v * CAP + (lane & (CAP - 1))];

    float4 sum = make_float4(0.f, 0.f, 0.f, 0.f);
    for (int e = 0; e < deg; e += 8) {
        const int i0 = e + q, i1 = e + 4 + q;
        const int s0 = __shfl(si, i0 & (CAP - 1));
        const int s1 = __shfl(si, i1 & (CAP - 1));
        unsigned x0 = 0u, x1 = 0u;
        if (i0 < deg) x0 = emb8[(unsigned)s0 * 16 + c];
        if (i1 < deg) x1 = emb8[(unsigned)s1 * 16 + c];
        const f32x2 a0 = __builtin_amdgcn_cvt_pk_f32_fp8((int)x0, false);
        const f32x2 a1 = __builtin_amdgcn_cvt_pk_f32_fp8((int)x0, true);
        const f32x2 b0 = __builtin_amdgcn_cvt_pk_f32_fp8((int)x1, false);
        const f32x2 b1 = __builtin_amdgcn_cvt_pk_f32_fp8((int)x1, true);
        sum.x += a0.x + b0.x;
        sum.y += a0.y + b0.y;
        sum.z += a1.x + b1.x;
        sum.w += a1.y + b1.y;
    }
#pragma unroll
    for (int off = 16; off < 64; off <<= 1) {
        sum.x += __shfl_xor(sum.x, off);
        sum.y += __shfl_xor(sum.y, off);
        sum.z += __shfl_xor(sum.z, off);
        sum.w += __shfl_xor(sum.w, off);
    }
    if (q == 0) {
        *(s16x4*)&acc16[v * D + c * 4] = f2bf4(sum);
    }
}

// Overflow edges: single wave, fully serial over the (tiny) list -> no race
// on the bf16 read-modify-write. lane l owns dim l.
__global__ __launch_bounds__(64) void ovf2_kernel(
    const float* __restrict__ emb, const int* __restrict__ ovf_cnt,
    const int2* __restrict__ ovf, short* __restrict__ acc16) {
    int n = *ovf_cnt;
    if (n > OVF_CAP) n = OVF_CAP;
    const int l = threadIdx.x;
    for (int i = 0; i < n; ++i) {
        const int2 e = ovf[i];
        const float a = bf2f(acc16[e.y * D + l]) + emb[e.x * D + l];
        acc16[e.y * D + l] = f2bf(a);
    }
}

// ---------------------------------------------------------------------------
// Legacy region fill + f32 gather + f32 ovf (mid tier / fallback only).
// ---------------------------------------------------------------------------
__global__ __launch_bounds__(256) void fill_kernel(
    const int* __restrict__ edge_src, const int* __restrict__ edge_dst,
    int* __restrict__ cnt, int* __restrict__ slots,
    int* __restrict__ ovf_cnt, int2* __restrict__ ovf) {
    const int r = blockIdx.x & (NR - 1);
    if (r == 7) return;
    const int slice = blockIdx.x >> 3;
    const int base_e = slice * SLICE_EDGES + threadIdx.x * 8;
    if (base_e >= N_EDGES) return;
    const vint4* s4 = (const vint4*)(edge_src + base_e);
    const vint4* d4 = (const vint4*)(edge_dst + base_e);
    vint4 a0 = __builtin_nontemporal_load(s4);
    vint4 a1 = __builtin_nontemporal_load(s4 + 1);
    vint4 b0 = __builtin_nontemporal_load(d4);
    vint4 b1 = __builtin_nontemporal_load(d4 + 1);
    int ss[8] = {a0.x, a0.y, a0.z, a0.w, a1.x, a1.y, a1.z, a1.w};
    int dd[8] = {b0.x, b0.y, b0.z, b0.w, b1.x, b1.y, b1.z, b1.w};
    int pos[8];
#pragma unroll
    for (int i = 0; i < 8; ++i) {
        pos[i] = ((dd[i] >> 14) == r) ? atomicAdd(&cnt[dd[i]], 1) : -1;
    }
#pragma unroll
    for (int i = 0; i < 8; ++i) {
        if (pos[i] >= 0 && pos[i] < CAP) slots[dd[i] * CAP + pos[i]] = ss[i];
    }
#pragma unroll
    for (int i = 0; i < 8; ++i) {
        if (pos[i] >= CAP) {
            int j = atomicAdd(ovf_cnt, 1);
            if (j < OVF_CAP) ovf[j] = make_int2(ss[i], dd[i]);
        }
    }
}

__global__ __launch_bounds__(256) void gather_kernel(
    const float* __restrict__ emb, const int* __restrict__ cnt,
    const int* __restrict__ slots, float* __restrict__ acc) {
    const int lane = threadIdx.x & 63;
    const int wave = threadIdx.x >> 6;
    const int v = blockIdx.x * 4 + wave;
    const int q  = lane >> 4;
    const int c4 = lane & 15;
    int deg = cnt[v];
    if (deg > CAP) deg = CAP;
    const int si = slots[v * CAP + (lane & (CAP - 1))];
    const float4* emb4 = (const float4*)emb;

    float4 sum = make_float4(0.f, 0.f, 0.f, 0.f);
    for (int e = 0; e < deg; e += 4) {
        const int idx = e + q;
        const int s = __shfl(si, idx & (CAP - 1));
        if (idx < deg) {
            float4 a = emb4[s * 16 + c4];
            sum.x += a.x; sum.y += a.y; sum.z += a.z; sum.w += a.w;
        }
    }
#pragma unroll
    for (int off = 16; off < 64; off <<= 1) {
        sum.x += __shfl_xor(sum.x, off);
        sum.y += __shfl_xor(sum.y, off);
        sum.z += __shfl_xor(sum.z, off);
        sum.w += __shfl_xor(sum.w, off);
    }
    if (q == 0) {
        ((float4*)acc)[v * 16 + c4] = sum;
    }
}

__global__ __launch_bounds__(256) void ovf_kernel(
    const float* __restrict__ emb, const int* __restrict__ ovf_cnt,
    const int2* __restrict__ ovf, float* __restrict__ acc) {
    int n = *ovf_cnt;
    if (n > OVF_CAP) n = OVF_CAP;
    const int lane = threadIdx.x & 63;
    const int wv = (blockIdx.x * 256 + threadIdx.x) >> 6;
    const int nwaves = (gridDim.x * 256) >> 6;
    for (int i = wv; i < n; i += nwaves) {
        int2 e = ovf[i];
        unsafeAtomicAdd(&acc[e.y * D + lane], emb[e.x * D + lane]);
    }
}

__global__ __launch_bounds__(256) void scatter_kernel(
    const float* __restrict__ emb,
    const int* __restrict__ edge_src, const int* __restrict__ edge_dst,
    float* __restrict__ acc) {
    int gid = blockIdx.x * 256 + threadIdx.x;
    int e = gid >> 6;
    int c = gid & 63;
    unsafeAtomicAdd(&acc[edge_dst[e] * D + c], emb[edge_src[e] * D + c]);
}

// ---------------------------------------------------------------------------
// R15 final: all inputs pre-converted bf16 (feat16/acc16/w16) -> LDS staging
// is pure s16x8 copies, zero cvt VALU, and input traffic halves (51.2 ->
// 25.6 MB). MFMA z = [feat|nbr] @ [W1|W2]^T, K=128, 16x16x32, 4 k-steps.
// Fragment layouts m89/m120-verified (carried from the f32 version).
// ---------------------------------------------------------------------------
__global__ __launch_bounds__(256) void final16_kernel(
    const short* __restrict__ feat16, const short* __restrict__ acc16,
    const short* __restrict__ w16, const float* __restrict__ b1,
    const float* __restrict__ b2, float* __restrict__ partials) {
    __shared__ short A_s[64 * ASTRIDE];
    __shared__ short W_s[64 * ASTRIDE];
    __shared__ float red[4][64];

    const int tid  = threadIdx.x;
    const int lane = tid & 63;
    const int wave = tid >> 6;
    const int quad = lane >> 4;
    const int col  = lane & 15;
    const int node0 = blockIdx.x * 64;

    float bias[4];
#pragma unroll
    for (int nb = 0; nb < 4; ++nb) {
        const int o = nb * 16 + col;
        bias[nb] = b1[o] + b2[o];
    }

    // Stage W: 1024 s16x8 copies (w16 already in W_s layout).
#pragma unroll
    for (int i = 0; i < 4; ++i) {
        const int flat = tid + i * 256;          // 0..1023
        const int row = flat >> 4, c = flat & 15;
        *(s16x8*)&W_s[row * ASTRIDE + c * 8] = *(const s16x8*)&w16[flat * 8];
    }

    // Stage A: row = node, chunks 0-7 feat16, 8-15 acc16. Pure copies.
#pragma unroll
    for (int i = 0; i < 4; ++i) {
        const int flat = tid + i * 256;
        const int row = flat >> 4, c = flat & 15;
        const int node = node0 + row;
        s16x8 pk = {0, 0, 0, 0, 0, 0, 0, 0};
        if (node < N_NODES) {
            pk = (c < 8) ? *(const s16x8*)&feat16[node * D + c * 8]
                         : *(const s16x8*)&acc16[node * D + (c - 8) * 8];
        }
        *(s16x8*)&A_s[row * ASTRIDE + c * 8] = pk;
    }
    __syncthreads();

    bf16x8 Bf[4][4];
#pragma unroll
    for (int nb = 0; nb < 4; ++nb)
#pragma unroll
        for (int ks = 0; ks < 4; ++ks)
            Bf[nb][ks] = __builtin_bit_cast(bf16x8,
                *(const s16x8*)&W_s[(nb * 16 + col) * ASTRIDE + ks * 32 + quad * 8]);

    f32x4 C[4];
#pragma unroll
    for (int nb = 0; nb < 4; ++nb) C[nb] = (f32x4){0.f, 0.f, 0.f, 0.f};
#pragma unroll
    for (int ks = 0; ks < 4; ++ks) {
        const bf16x8 Af = __builtin_bit_cast(bf16x8,
            *(const s16x8*)&A_s[(wave * 16 + col) * ASTRIDE + ks * 32 + quad * 8]);
#pragma unroll
        for (int nb = 0; nb < 4; ++nb)
            C[nb] = __builtin_amdgcn_mfma_f32_16x16x32_bf16(Af, Bf[nb][ks],
                                                            C[nb], 0, 0, 0);
    }

    float sums[4] = {0.f, 0.f, 0.f, 0.f};
#pragma unroll
    for (int nb = 0; nb < 4; ++nb) {
#pragma unroll
        for (int reg = 0; reg < 4; ++reg) {
            const int node = node0 + wave * 16 + quad * 4 + reg;
            float u = C[nb][reg] + bias[nb];
            u = (u > 0.f) ? u : 0.f;
            if (node < N_NODES) sums[nb] += u;
        }
        sums[nb] += __shfl_xor(sums[nb], 16);
        sums[nb] += __shfl_xor(sums[nb], 32);
        if (lane < 16) red[wave][nb * 16 + lane] = sums[nb];
    }
    __syncthreads();
    if (tid < 64) {
        partials[blockIdx.x * 64 + tid] =
            red[0][tid] + red[1][tid] + red[2][tid] + red[3][tid];
    }
}

// ---------------------------------------------------------------------------
// Legacy f32-input final (mid tier / fallback).
// ---------------------------------------------------------------------------
__global__ __launch_bounds__(256) void final_kernel(
    const float* __restrict__ feat, const float* __restrict__ acc,
    const float* __restrict__ W1, const float* __restrict__ b1,
    const float* __restrict__ W2, const float* __restrict__ b2,
    float* __restrict__ partials) {
    __shared__ short A_s[64 * ASTRIDE];
    __shared__ short W_s[64 * ASTRIDE];
    __shared__ float red[4][64];

    const int tid  = threadIdx.x;
    const int lane = tid & 63;
    const int wave = tid >> 6;
    const int quad = lane >> 4;
    const int col  = lane & 15;
    const int node0 = blockIdx.x * 64;

    float bias[4];
#pragma unroll
    for (int nb = 0; nb < 4; ++nb) {
        const int o = nb * 16 + col;
        bias[nb] = b1[o] + b2[o];
    }

    {
        const float4* W1v = (const float4*)W1;
        const float4* W2v = (const float4*)W2;
#pragma unroll
        for (int i = 0; i < 4; ++i) {
            const int flat = tid + i * 256;
            const int row = flat >> 4, c4 = flat & 15;
            *(s16x4*)&W_s[row * ASTRIDE + c4 * 4]      = f2bf4(W1v[flat]);
            *(s16x4*)&W_s[row * ASTRIDE + 64 + c4 * 4] = f2bf4(W2v[flat]);
        }
    }

    {
        const float4* fv = (const float4*)feat;
        const float4* av = (const float4*)acc;
#pragma unroll
        for (int i = 0; i < 4; ++i) {
            const int flat = tid + i * 256;
            const int row = flat >> 4, c4 = flat & 15;
            const int node = node0 + row;
            float4 f = make_float4(0.f, 0.f, 0.f, 0.f);
            float4 n = make_float4(0.f, 0.f, 0.f, 0.f);
            if (node < N_NODES) {
                f = fv[(size_t)node * 16 + c4];
                n = av[(size_t)node * 16 + c4];
            }
            *(s16x4*)&A_s[row * ASTRIDE + c4 * 4]      = f2bf4(f);
            *(s16x4*)&A_s[row * ASTRIDE + 64 + c4 * 4] = f2bf4(n);
        }
    }
    __syncthreads();

    bf16x8 Bf[4][4];
#pragma unroll
    for (int nb = 0; nb < 4; ++nb)
#pragma unroll
        for (int ks = 0; ks < 4; ++ks)
            Bf[nb][ks] = __builtin_bit_cast(bf16x8,
                *(const s16x8*)&W_s[(nb * 16 + col) * ASTRIDE + ks * 32 + quad * 8]);

    f32x4 C[4];
#pragma unroll
    for (int nb = 0; nb < 4; ++nb) C[nb] = (f32x4){0.f, 0.f, 0.f, 0.f};
#pragma unroll
    for (int ks = 0; ks < 4; ++ks) {
        const bf16x8 Af = __builtin_bit_cast(bf16x8,
            *(const s16x8*)&A_s[(wave * 16 + col) * ASTRIDE + ks * 32 + quad * 8]);
#pragma unroll
        for (int nb = 0; nb < 4; ++nb)
            C[nb] = __builtin_amdgcn_mfma_f32_16x16x32_bf16(Af, Bf[nb][ks],
                                                            C[nb], 0, 0, 0);
    }

    float sums[4] = {0.f, 0.f, 0.f, 0.f};
#pragma unroll
    for (int nb = 0; nb < 4; ++nb) {
#pragma unroll
        for (int reg = 0; reg < 4; ++reg) {
            const int node = node0 + wave * 16 + quad * 4 + reg;
            float u = C[nb][reg] + bias[nb];
            u = (u > 0.f) ? u : 0.f;
            if (node < N_NODES) sums[nb] += u;
        }
        sums[nb] += __shfl_xor(sums[nb], 16);
        sums[nb] += __shfl_xor(sums[nb], 32);
        if (lane < 16) red[wave][nb * 16 + lane] = sums[nb];
    }
    __syncthreads();
    if (tid < 64) {
        partials[blockIdx.x * 64 + tid] =
            red[0][tid] + red[1][tid] + red[2][tid] + red[3][tid];
    }
}

// ---------------------------------------------------------------------------
// Two-stage partials reduction (R9-proven).
// ---------------------------------------------------------------------------
__global__ __launch_bounds__(256) void reduce1_kernel(
    const float* __restrict__ partials, float* __restrict__ part2) {
    __shared__ float red[4][64];
    const int col = threadIdx.x & 63;
    const int seg = threadIdx.x >> 6;
    const int r0 = blockIdx.x * R1_ROWS;
    int r1 = r0 + R1_ROWS;
    if (r1 > N_TILES) r1 = N_TILES;
    float s = 0.f;
    for (int r = r0 + seg; r < r1; r += 4) s += partials[r * 64 + col];
    red[seg][col] = s;
    __syncthreads();
    if (seg == 0) {
        part2[blockIdx.x * 64 + col] =
            red[0][col] + red[1][col] + red[2][col] + red[3][col];
    }
}

__global__ __launch_bounds__(256) void reduce2_kernel(
    const float* __restrict__ part2, float* __restrict__ out) {
    __shared__ float red[4][64];
    const int col = threadIdx.x & 63;
    const int seg = threadIdx.x >> 6;
    float s = 0.f;
    for (int r = seg; r < R1_BLOCKS; r += 4) s += part2[r * 64 + col];
    red[seg][col] = s;
    __syncthreads();
    if (seg == 0) {
        out[col] = red[0][col] + red[1][col] + red[2][col] + red[3][col];
    }
}

extern "C" void kernel_launch(void* const* d_in, const int* in_sizes, int n_in,
                              void* d_out, int out_size, void* d_ws, size_t ws_size,
                              hipStream_t stream) {
    const float* feat = (const float*)d_in[0];
    const float* emb  = (const float*)d_in[1];
    const float* W1   = (const float*)d_in[2];
    const float* b1   = (const float*)d_in[3];
    const float* W2   = (const float*)d_in[4];
    const float* b2   = (const float*)d_in[5];
    const int* edge_src = (const int*)d_in[6];
    const int* edge_dst = (const int*)d_in[7];
    float* out = (float*)d_out;
    char* ws = (char*)d_ws;

    if (ws_size >= (size_t)WS_NEEDED16) {
        // R15 path. bkt aliased into acc16's region (dead once gather8
        // rewrites all of acc16); bcnt aliased into partials.
        int*      cnt      = (int*)ws;
        int*      slots    = (int*)(ws + WS_SLOTS_OFF);
        short*    acc16    = (short*)(ws + WS_ACC16_OFF);
        int*      bkt      = (int*)(ws + WS_ACC16_OFF);
        short*    feat16   = (short*)(ws + WS_FEAT16_OFF);
        int*      ovf_cnt  = (int*)(ws + WS_OVFC_OFF);
        int2*     ovf      = (int2*)(ws + WS_OVF_OFF);
        float*    partials = (float*)(ws + WS_PART_OFF);
        int*      bcnt     = (int*)(ws + WS_PART_OFF);
        float*    part2    = (float*)(ws + WS_PART2_OFF);
        unsigned* emb8     = (unsigned*)(ws + WS_EMB8_OFF);
        short*    w16      = (short*)(ws + WS_W16_OFF);

        (void)hipMemsetAsync(ovf_cnt, 0, sizeof(int), stream);
        (void)hipMemsetAsync(bcnt, 0, NB2 * sizeof(int), stream);

        part_kernel<<<P1_BLOCKS + CVT_BLOCKS, 512, 0, stream>>>(
            edge_src, edge_dst, bcnt, bkt, ovf_cnt, ovf,
            emb, emb8, feat, feat16, W1, W2, w16);
        fill2_kernel<<<NB2, 512, 0, stream>>>(bcnt, bkt, cnt, slots,
                                              ovf_cnt, ovf);
        gather8_kernel<<<N_NODES / 4, 256, 0, stream>>>(emb8, cnt, slots, acc16);
        ovf2_kernel<<<1, 64, 0, stream>>>(emb, ovf_cnt, ovf, acc16);

        final16_kernel<<<N_TILES, 256, 0, stream>>>(feat16, acc16, w16,
                                                    b1, b2, partials);
        reduce1_kernel<<<R1_BLOCKS, 256, 0, stream>>>(partials, part2);
        reduce2_kernel<<<1, 256, 0, stream>>>(part2, out);
    } else if (ws_size >= (size_t)WS_NEEDED) {
        int*   cnt      = (int*)ws;
        int*   slots    = (int*)(ws + WS_SLOTS_OFF);
        float* acc      = (float*)(ws + WS_ACC_OFF);
        int*   ovf_cnt  = (int*)(ws + WS_OVFC_OFF);
        int2*  ovf      = (int2*)(ws + WS_OVF_OFF);
        float* partials = (float*)(ws + WS_PART_OFF);
        float* part2    = (float*)(ws + WS_PART2_OFF);

        (void)hipMemsetAsync(cnt, 0, N_NODES * sizeof(int), stream);
        (void)hipMemsetAsync(ovf_cnt, 0, sizeof(int), stream);

        fill_kernel<<<NR * N_SLICES, 256, 0, stream>>>(edge_src, edge_dst,
                                                       cnt, slots, ovf_cnt, ovf);
        gather_kernel<<<N_NODES / 4, 256, 0, stream>>>(emb, cnt, slots, acc);
        ovf_kernel<<<16, 256, 0, stream>>>(emb, ovf_cnt, ovf, acc);

        final_kernel<<<N_TILES, 256, 0, stream>>>(feat, acc, W1, b1, W2, b2,
                                                  partials);
        reduce1_kernel<<<R1_BLOCKS, 256, 0, stream>>>(partials, part2);
        reduce2_kernel<<<1, 256, 0, stream>>>(part2, out);
    } else {
        float* acc = (float*)ws;
        (void)hipMemsetAsync(acc, 0, (size_t)N_NODES * D * sizeof(float), stream);
        scatter_kernel<<<(N_EDGES * 64) / 256, 256, 0, stream>>>(emb, edge_src,
                                                                 edge_dst, acc);
        float* partials = (float*)(ws + (size_t)N_NODES * D * sizeof(float));
        float* part2    = partials + (size_t)N_TILES * 64;
        final_kernel<<<N_TILES, 256, 0, stream>>>(feat, acc, W1, b1, W2, b2,
                                                  partials);
        reduce1_kernel<<<R1_BLOCKS, 256, 0, stream>>>(partials, part2);
        reduce2_kernel<<<1, 256, 0, stream>>>(part2, out);
    }
}

// Round 7
// 191.722 us; speedup vs baseline: 1.0308x; 1.0308x over previous
//
#include <hip/hip_runtime.h>

#define N_NODES 100000
#define N_EDGES 1600000
#define D 64
#define CAP 32         // slot cap per node; Poisson(16): P(deg>32)~1e-5/node, ovf backstops
#define OVF_CAP 8192   // overflow edge list (backstop)
#define N_TILES 1563   // (N_NODES + 63) / 64
#define NR 8           // (legacy fill) region groups
#define SLICE_EDGES 2048
#define N_SLICES 782   // ceil(N_EDGES / SLICE_EDGES)
#define R1_BLOCKS 64   // stage-1 reduce blocks
#define R1_ROWS 25     // ceil(N_TILES / R1_BLOCKS)
#define ASTRIDE 136    // final LDS row stride in bf16 elems (128 + 8 pad)

// Bucketed partition (R12-proven) + CSR fill (R11-proven, 128-node buckets)
#define NB2 782        // buckets of 128 nodes (dst>>7)
#define BCAP2 2560     // per-bucket capacity (mean 2048, sigma~45 -> +11 sigma)
#define EPB 8192       // edges per partition block
#define P1_BLOCKS 196  // ceil(N_EDGES / EPB)
#define CVT_BLOCKS 64  // rider blocks: emb->fp8 ONLY (R15's feat/W riders cost
                       // +12us of unhidden traffic — reverted, R16)

typedef int    vint4  __attribute__((ext_vector_type(4)));
typedef short  s16x4  __attribute__((ext_vector_type(4)));
typedef short  s16x8  __attribute__((ext_vector_type(8)));
typedef float  f32x2  __attribute__((ext_vector_type(2)));
typedef float  f32x4  __attribute__((ext_vector_type(4)));
typedef __bf16 bf16x8 __attribute__((ext_vector_type(8)));  // MFMA operand type

// f32 -> bf16 (RNE). Inputs are finite; NaN path not needed.
__device__ inline short f2bf(float f) {
    unsigned u = __builtin_bit_cast(unsigned, f);
    u += 0x7fffu + ((u >> 16) & 1u);
    return (short)(u >> 16);
}
__device__ inline s16x4 f2bf4(float4 v) {
    s16x4 r; r.x = f2bf(v.x); r.y = f2bf(v.y); r.z = f2bf(v.z); r.w = f2bf(v.w);
    return r;
}
__device__ inline float bf2f(short s) {
    return __builtin_bit_cast(float, ((unsigned)(unsigned short)s) << 16);
}

// ws layout (bytes), top tier:
//   cnt    @ 0        : N_NODES int           (0.4 MB)
//   slots  @ 401408   : N_NODES*CAP int       (12.8 MB)
//   acc16  @ 13201408 : N_NODES*D bf16        (12.8 MB) [bkt 8MB aliased pre-gather]
//   ovfc   @ 38801408 : int
//   ovf    @ 38801424 : OVF_CAP int2
//   part   @ 38867200 : N_TILES*64 float      (0.4 MB)  [bcnt aliased pre-final]
//   part2  @ 39267328 : R1_BLOCKS*64 float    (16 KB)
//   emb8   @ 39283712 : N_NODES*D bytes       (6.4 MB, OCP e4m3)
#define WS_SLOTS_OFF  401408
#define WS_ACC_OFF    13201408   // mid-tier f32 acc lives here (25.6 MB)
#define WS_ACC16_OFF  13201408
#define WS_OVFC_OFF   38801408
#define WS_OVF_OFF    38801424
#define WS_PART_OFF   38867200
#define WS_PART2_OFF  39267328
#define WS_EMB8_OFF   39283712
#define WS_NEEDED     (WS_PART2_OFF + R1_BLOCKS * 64 * 4)
#define WS_NEEDED16   (WS_EMB8_OFF + N_NODES * D * 2)

// ---------------------------------------------------------------------------
// R12-proven pass 1: edge partition into 782 dst-buckets (128 nodes each).
// Read 8192 edges once -> LDS histogram -> 1024-wide ping-pong scan ->
// LDS-cursor scatter (+bid) -> one global atomicAdd per (block,bucket) ->
// one-thread-per-edge coalesced copy out. pk = (src<<7)|(dst&127).
// Rider blocks (>= P1_BLOCKS): emb -> OCP e4m3 via HW cvt_pk_fp8 only.
// ---------------------------------------------------------------------------
__global__ __launch_bounds__(512) void part_kernel(
    const int* __restrict__ edge_src, const int* __restrict__ edge_dst,
    int* __restrict__ bcnt, int* __restrict__ bkt,
    int* __restrict__ ovf_cnt, int2* __restrict__ ovf,
    const float* __restrict__ emb, unsigned* __restrict__ emb8) {
    const int tid = threadIdx.x;
    if (blockIdx.x >= P1_BLOCKS) {
        const float4* e4 = (const float4*)emb;
        const unsigned t0 = (blockIdx.x - P1_BLOCKS) * 512 + tid;
        for (unsigned j = t0; j < (unsigned)(N_NODES * D / 4);
             j += CVT_BLOCKS * 512) {
            float4 v = e4[j];
            int w = 0;
            w = __builtin_amdgcn_cvt_pk_fp8_f32(v.x, v.y, w, false);
            w = __builtin_amdgcn_cvt_pk_fp8_f32(v.z, v.w, w, true);
            emb8[j] = (unsigned)w;
        }
        return;
    }

    __shared__ int stage[EPB];
    __shared__ unsigned short bid[EPB];
    __shared__ int scA[1024];
    __shared__ int scB[1024];
    __shared__ int hist[NB2];
    int* const cur   = scB;   // dead after scan
    int* const gbase = scA;   // dead after tot/cur captured

    const int e0 = blockIdx.x * EPB;
    for (int i = tid; i < NB2; i += 512) hist[i] = 0;
    __syncthreads();

    int ss[16], dd[16];
#pragma unroll
    for (int i = 0; i < 16; ++i) {
        const int e = e0 + i * 512 + tid;
        if (e < N_EDGES) { ss[i] = edge_src[e]; dd[i] = edge_dst[e]; }
        else             { ss[i] = 0; dd[i] = -1; }
    }

#pragma unroll
    for (int i = 0; i < 16; ++i)
        if (dd[i] >= 0) atomicAdd(&hist[dd[i] >> 7], 1);
    __syncthreads();

    scA[tid]       = (tid < NB2) ? hist[tid] : 0;
    scA[tid + 512] = 0;
    if (tid + 512 < NB2) scA[tid + 512] = hist[tid + 512];
    __syncthreads();
    {
        int* sA = scA;
        int* sB = scB;
        for (int off = 1; off < 1024; off <<= 1) {
            const int i1 = tid + 512;
            const int v0 = sA[tid] + ((tid >= off) ? sA[tid - off] : 0);
            const int v1 = sA[i1] + sA[i1 - off];
            sB[tid] = v0; sB[i1] = v1;
            __syncthreads();
            int* t = sA; sA = sB; sB = t;
        }
    }
    const int tot = scA[NB2 - 1];
    for (int i = tid; i < NB2; i += 512) cur[i] = scA[i] - hist[i];
    __syncthreads();

#pragma unroll
    for (int i = 0; i < 16; ++i) {
        if (dd[i] >= 0) {
            const int b = dd[i] >> 7;
            const int pos = atomicAdd(&cur[b], 1);
            stage[pos] = (ss[i] << 7) | (dd[i] & 127);
            bid[pos] = (unsigned short)b;
        }
    }
    for (int i = tid; i < NB2; i += 512)
        gbase[i] = atomicAdd(&bcnt[i], hist[i]);
    __syncthreads();

    for (int j = tid; j < tot; j += 512) {
        const int pk = stage[j];
        const int b  = bid[j];
        const int gpos = gbase[b] + (j - (cur[b] - hist[b]));
        if (gpos < BCAP2) {
            bkt[b * BCAP2 + gpos] = pk;
        } else {
            int oj = atomicAdd(ovf_cnt, 1);
            if (oj < OVF_CAP) ovf[oj] = make_int2(pk >> 7, (b << 7) | (pk & 127));
        }
    }
}

// ---------------------------------------------------------------------------
// R11-proven pass 2 (128-node buckets): owned CSR fill. Per-node cursors in
// LDS via int atomicAdd on a DIRECT __shared__ array (ds_add_rtn_u32 fast
// path — R3's disaster was float no-return atomics through a generic ptr).
// ---------------------------------------------------------------------------
__global__ __launch_bounds__(512) void fill2_kernel(
    const int* __restrict__ bcnt, const int* __restrict__ bkt,
    int* __restrict__ cnt, int* __restrict__ slots,
    int* __restrict__ ovf_cnt, int2* __restrict__ ovf) {
    __shared__ int lcnt[128];
    const int b = blockIdx.x;
    const int tid = threadIdx.x;
    if (tid < 128) lcnt[tid] = 0;
    __syncthreads();
    int n = bcnt[b];
    if (n > BCAP2) n = BCAP2;
    for (int i = tid; i < n; i += 512) {
        const int pk = bkt[b * BCAP2 + i];
        const int dl = pk & 127;
        const int pos = atomicAdd(&lcnt[dl], 1);   // LDS int atomic (fast path)
        const int v = (b << 7) | dl;
        if (pos < CAP) {
            slots[v * CAP + pos] = pk >> 7;
        } else {
            int j = atomicAdd(ovf_cnt, 1);
            if (j < OVF_CAP) ovf[j] = make_int2(pk >> 7, v);
        }
    }
    __syncthreads();
    if (tid < 128) {
        const int v = (b << 7) | tid;
        if (v < N_NODES) cnt[v] = lcnt[tid];
    }
}

// ---------------------------------------------------------------------------
// R16 gather: HW fp8 decode; FIXED-TRIP unroll over CAP (4 iters, masked
// loads) so all scattered loads issue together (no runtime-deg loop carry —
// attacks the latency residual R4 identified). Writes acc16 bf16 at the
// producer (free: halves gather WRITE and final's acc read).
// ---------------------------------------------------------------------------
__global__ __launch_bounds__(256) void gather8_kernel(
    const unsigned* __restrict__ emb8, const int* __restrict__ cnt,
    const int* __restrict__ slots, short* __restrict__ acc16) {
    const int lane = threadIdx.x & 63;
    const int wave = threadIdx.x >> 6;
    const int v = blockIdx.x * 4 + wave;
    const int q = lane >> 4;
    const int c = lane & 15;
    int deg = cnt[v];
    if (deg > CAP) deg = CAP;
    const int si = slots[v * CAP + (lane & (CAP - 1))];

    float4 sum = make_float4(0.f, 0.f, 0.f, 0.f);
#pragma unroll
    for (int e = 0; e < CAP; e += 8) {
        const int i0 = e + q, i1 = e + 4 + q;
        const int s0 = __shfl(si, i0);
        const int s1 = __shfl(si, i1);
        unsigned x0 = 0u, x1 = 0u;
        if (i0 < deg) x0 = emb8[(unsigned)s0 * 16 + c];
        if (i1 < deg) x1 = emb8[(unsigned)s1 * 16 + c];
        const f32x2 a0 = __builtin_amdgcn_cvt_pk_f32_fp8((int)x0, false);
        const f32x2 a1 = __builtin_amdgcn_cvt_pk_f32_fp8((int)x0, true);
        const f32x2 b0 = __builtin_amdgcn_cvt_pk_f32_fp8((int)x1, false);
        const f32x2 b1 = __builtin_amdgcn_cvt_pk_f32_fp8((int)x1, true);
        sum.x += a0.x + b0.x;
        sum.y += a0.y + b0.y;
        sum.z += a1.x + b1.x;
        sum.w += a1.y + b1.y;
    }
#pragma unroll
    for (int off = 16; off < 64; off <<= 1) {
        sum.x += __shfl_xor(sum.x, off);
        sum.y += __shfl_xor(sum.y, off);
        sum.z += __shfl_xor(sum.z, off);
        sum.w += __shfl_xor(sum.w, off);
    }
    if (q == 0) {
        *(s16x4*)&acc16[v * D + c * 4] = f2bf4(sum);
    }
}

// Overflow edges: single wave, fully serial over the (tiny) list -> no race
// on the bf16 read-modify-write. lane l owns dim l. (R15-proven.)
__global__ __launch_bounds__(64) void ovf2_kernel(
    const float* __restrict__ emb, const int* __restrict__ ovf_cnt,
    const int2* __restrict__ ovf, short* __restrict__ acc16) {
    int n = *ovf_cnt;
    if (n > OVF_CAP) n = OVF_CAP;
    const int l = threadIdx.x;
    for (int i = 0; i < n; ++i) {
        const int2 e = ovf[i];
        const float a = bf2f(acc16[e.y * D + l]) + emb[e.x * D + l];
        acc16[e.y * D + l] = f2bf(a);
    }
}

// ---------------------------------------------------------------------------
// Legacy region fill + f32 gather + f32 ovf (mid tier / fallback only).
// ---------------------------------------------------------------------------
__global__ __launch_bounds__(256) void fill_kernel(
    const int* __restrict__ edge_src, const int* __restrict__ edge_dst,
    int* __restrict__ cnt, int* __restrict__ slots,
    int* __restrict__ ovf_cnt, int2* __restrict__ ovf) {
    const int r = blockIdx.x & (NR - 1);
    if (r == 7) return;
    const int slice = blockIdx.x >> 3;
    const int base_e = slice * SLICE_EDGES + threadIdx.x * 8;
    if (base_e >= N_EDGES) return;
    const vint4* s4 = (const vint4*)(edge_src + base_e);
    const vint4* d4 = (const vint4*)(edge_dst + base_e);
    vint4 a0 = __builtin_nontemporal_load(s4);
    vint4 a1 = __builtin_nontemporal_load(s4 + 1);
    vint4 b0 = __builtin_nontemporal_load(d4);
    vint4 b1 = __builtin_nontemporal_load(d4 + 1);
    int ss[8] = {a0.x, a0.y, a0.z, a0.w, a1.x, a1.y, a1.z, a1.w};
    int dd[8] = {b0.x, b0.y, b0.z, b0.w, b1.x, b1.y, b1.z, b1.w};
    int pos[8];
#pragma unroll
    for (int i = 0; i < 8; ++i) {
        pos[i] = ((dd[i] >> 14) == r) ? atomicAdd(&cnt[dd[i]], 1) : -1;
    }
#pragma unroll
    for (int i = 0; i < 8; ++i) {
        if (pos[i] >= 0 && pos[i] < CAP) slots[dd[i] * CAP + pos[i]] = ss[i];
    }
#pragma unroll
    for (int i = 0; i < 8; ++i) {
        if (pos[i] >= CAP) {
            int j = atomicAdd(ovf_cnt, 1);
            if (j < OVF_CAP) ovf[j] = make_int2(ss[i], dd[i]);
        }
    }
}

__global__ __launch_bounds__(256) void gather_kernel(
    const float* __restrict__ emb, const int* __restrict__ cnt,
    const int* __restrict__ slots, float* __restrict__ acc) {
    const int lane = threadIdx.x & 63;
    const int wave = threadIdx.x >> 6;
    const int v = blockIdx.x * 4 + wave;
    const int q  = lane >> 4;
    const int c4 = lane & 15;
    int deg = cnt[v];
    if (deg > CAP) deg = CAP;
    const int si = slots[v * CAP + (lane & (CAP - 1))];
    const float4* emb4 = (const float4*)emb;

    float4 sum = make_float4(0.f, 0.f, 0.f, 0.f);
    for (int e = 0; e < deg; e += 4) {
        const int idx = e + q;
        const int s = __shfl(si, idx & (CAP - 1));
        if (idx < deg) {
            float4 a = emb4[s * 16 + c4];
            sum.x += a.x; sum.y += a.y; sum.z += a.z; sum.w += a.w;
        }
    }
#pragma unroll
    for (int off = 16; off < 64; off <<= 1) {
        sum.x += __shfl_xor(sum.x, off);
        sum.y += __shfl_xor(sum.y, off);
        sum.z += __shfl_xor(sum.z, off);
        sum.w += __shfl_xor(sum.w, off);
    }
    if (q == 0) {
        ((float4*)acc)[v * 16 + c4] = sum;
    }
}

__global__ __launch_bounds__(256) void ovf_kernel(
    const float* __restrict__ emb, const int* __restrict__ ovf_cnt,
    const int2* __restrict__ ovf, float* __restrict__ acc) {
    int n = *ovf_cnt;
    if (n > OVF_CAP) n = OVF_CAP;
    const int lane = threadIdx.x & 63;
    const int wv = (blockIdx.x * 256 + threadIdx.x) >> 6;
    const int nwaves = (gridDim.x * 256) >> 6;
    for (int i = wv; i < n; i += nwaves) {
        int2 e = ovf[i];
        unsafeAtomicAdd(&acc[e.y * D + lane], emb[e.x * D + lane]);
    }
}

__global__ __launch_bounds__(256) void scatter_kernel(
    const float* __restrict__ emb,
    const int* __restrict__ edge_src, const int* __restrict__ edge_dst,
    float* __restrict__ acc) {
    int gid = blockIdx.x * 256 + threadIdx.x;
    int e = gid >> 6;
    int c = gid & 63;
    unsafeAtomicAdd(&acc[edge_dst[e] * D + c], emb[edge_src[e] * D + c]);
}

// ---------------------------------------------------------------------------
// R16 final: feat f32 (in-kernel cvt, same as the proven R14 final) +
// acc16 bf16 (pure s16x8 copies, no cvt, half the bytes) + W f32.
// Input traffic 51.2 -> 38.4 MB with zero added passes elsewhere.
// MFMA z = [feat|nbr] @ [W1|W2]^T, K=128, 16x16x32, 4 k-steps.
// Fragment layouts m89/m120-verified.
// ---------------------------------------------------------------------------
__global__ __launch_bounds__(256) void final_mixed_kernel(
    const float* __restrict__ feat, const short* __restrict__ acc16,
    const float* __restrict__ W1, const float* __restrict__ b1,
    const float* __restrict__ W2, const float* __restrict__ b2,
    float* __restrict__ partials) {
    __shared__ short A_s[64 * ASTRIDE];
    __shared__ short W_s[64 * ASTRIDE];
    __shared__ float red[4][64];

    const int tid  = threadIdx.x;
    const int lane = tid & 63;
    const int wave = tid >> 6;
    const int quad = lane >> 4;
    const int col  = lane & 15;
    const int node0 = blockIdx.x * 64;

    float bias[4];
#pragma unroll
    for (int nb = 0; nb < 4; ++nb) {
        const int o = nb * 16 + col;
        bias[nb] = b1[o] + b2[o];
    }

    // Stage W (f32 -> bf16): 1024 float4 per matrix, 4 per thread.
    {
        const float4* W1v = (const float4*)W1;
        const float4* W2v = (const float4*)W2;
#pragma unroll
        for (int i = 0; i < 4; ++i) {
            const int flat = tid + i * 256;   // 0..1023
            const int row = flat >> 4, c4 = flat & 15;
            *(s16x4*)&W_s[row * ASTRIDE + c4 * 4]      = f2bf4(W1v[flat]);
            *(s16x4*)&W_s[row * ASTRIDE + 64 + c4 * 4] = f2bf4(W2v[flat]);
        }
    }

    // Stage A, feat half (f32 -> bf16): 1024 float4 chunks.
    {
        const float4* fv = (const float4*)feat;
#pragma unroll
        for (int i = 0; i < 4; ++i) {
            const int flat = tid + i * 256;
            const int row = flat >> 4, c4 = flat & 15;
            const int node = node0 + row;
            float4 f = make_float4(0.f, 0.f, 0.f, 0.f);
            if (node < N_NODES) f = fv[(size_t)node * 16 + c4];
            *(s16x4*)&A_s[row * ASTRIDE + c4 * 4] = f2bf4(f);
        }
    }
    // Stage A, nbr half (bf16 pure copy): 512 s16x8 chunks.
    {
#pragma unroll
        for (int i = 0; i < 2; ++i) {
            const int flat = tid + i * 256;   // 0..511
            const int row = flat >> 3, c = flat & 7;
            const int node = node0 + row;
            s16x8 pk = {0, 0, 0, 0, 0, 0, 0, 0};
            if (node < N_NODES) pk = *(const s16x8*)&acc16[node * D + c * 8];
            *(s16x8*)&A_s[row * ASTRIDE + 64 + c * 8] = pk;
        }
    }
    __syncthreads();

    bf16x8 Bf[4][4];
#pragma unroll
    for (int nb = 0; nb < 4; ++nb)
#pragma unroll
        for (int ks = 0; ks < 4; ++ks)
            Bf[nb][ks] = __builtin_bit_cast(bf16x8,
                *(const s16x8*)&W_s[(nb * 16 + col) * ASTRIDE + ks * 32 + quad * 8]);

    f32x4 C[4];
#pragma unroll
    for (int nb = 0; nb < 4; ++nb) C[nb] = (f32x4){0.f, 0.f, 0.f, 0.f};
#pragma unroll
    for (int ks = 0; ks < 4; ++ks) {
        const bf16x8 Af = __builtin_bit_cast(bf16x8,
            *(const s16x8*)&A_s[(wave * 16 + col) * ASTRIDE + ks * 32 + quad * 8]);
#pragma unroll
        for (int nb = 0; nb < 4; ++nb)
            C[nb] = __builtin_amdgcn_mfma_f32_16x16x32_bf16(Af, Bf[nb][ks],
                                                            C[nb], 0, 0, 0);
    }

    float sums[4] = {0.f, 0.f, 0.f, 0.f};
#pragma unroll
    for (int nb = 0; nb < 4; ++nb) {
#pragma unroll
        for (int reg = 0; reg < 4; ++reg) {
            const int node = node0 + wave * 16 + quad * 4 + reg;
            float u = C[nb][reg] + bias[nb];
            u = (u > 0.f) ? u : 0.f;
            if (node < N_NODES) sums[nb] += u;
        }
        sums[nb] += __shfl_xor(sums[nb], 16);
        sums[nb] += __shfl_xor(sums[nb], 32);
        if (lane < 16) red[wave][nb * 16 + lane] = sums[nb];
    }
    __syncthreads();
    if (tid < 64) {
        partials[blockIdx.x * 64 + tid] =
            red[0][tid] + red[1][tid] + red[2][tid] + red[3][tid];
    }
}

// ---------------------------------------------------------------------------
// Legacy f32-input final (mid tier / fallback).
// ---------------------------------------------------------------------------
__global__ __launch_bounds__(256) void final_kernel(
    const float* __restrict__ feat, const float* __restrict__ acc,
    const float* __restrict__ W1, const float* __restrict__ b1,
    const float* __restrict__ W2, const float* __restrict__ b2,
    float* __restrict__ partials) {
    __shared__ short A_s[64 * ASTRIDE];
    __shared__ short W_s[64 * ASTRIDE];
    __shared__ float red[4][64];

    const int tid  = threadIdx.x;
    const int lane = tid & 63;
    const int wave = tid >> 6;
    const int quad = lane >> 4;
    const int col  = lane & 15;
    const int node0 = blockIdx.x * 64;

    float bias[4];
#pragma unroll
    for (int nb = 0; nb < 4; ++nb) {
        const int o = nb * 16 + col;
        bias[nb] = b1[o] + b2[o];
    }

    {
        const float4* W1v = (const float4*)W1;
        const float4* W2v = (const float4*)W2;
#pragma unroll
        for (int i = 0; i < 4; ++i) {
            const int flat = tid + i * 256;
            const int row = flat >> 4, c4 = flat & 15;
            *(s16x4*)&W_s[row * ASTRIDE + c4 * 4]      = f2bf4(W1v[flat]);
            *(s16x4*)&W_s[row * ASTRIDE + 64 + c4 * 4] = f2bf4(W2v[flat]);
        }
    }

    {
        const float4* fv = (const float4*)feat;
        const float4* av = (const float4*)acc;
#pragma unroll
        for (int i = 0; i < 4; ++i) {
            const int flat = tid + i * 256;
            const int row = flat >> 4, c4 = flat & 15;
            const int node = node0 + row;
            float4 f = make_float4(0.f, 0.f, 0.f, 0.f);
            float4 n = make_float4(0.f, 0.f, 0.f, 0.f);
            if (node < N_NODES) {
                f = fv[(size_t)node * 16 + c4];
                n = av[(size_t)node * 16 + c4];
            }
            *(s16x4*)&A_s[row * ASTRIDE + c4 * 4]      = f2bf4(f);
            *(s16x4*)&A_s[row * ASTRIDE + 64 + c4 * 4] = f2bf4(n);
        }
    }
    __syncthreads();

    bf16x8 Bf[4][4];
#pragma unroll
    for (int nb = 0; nb < 4; ++nb)
#pragma unroll
        for (int ks = 0; ks < 4; ++ks)
            Bf[nb][ks] = __builtin_bit_cast(bf16x8,
                *(const s16x8*)&W_s[(nb * 16 + col) * ASTRIDE + ks * 32 + quad * 8]);

    f32x4 C[4];
#pragma unroll
    for (int nb = 0; nb < 4; ++nb) C[nb] = (f32x4){0.f, 0.f, 0.f, 0.f};
#pragma unroll
    for (int ks = 0; ks < 4; ++ks) {
        const bf16x8 Af = __builtin_bit_cast(bf16x8,
            *(const s16x8*)&A_s[(wave * 16 + col) * ASTRIDE + ks * 32 + quad * 8]);
#pragma unroll
        for (int nb = 0; nb < 4; ++nb)
            C[nb] = __builtin_amdgcn_mfma_f32_16x16x32_bf16(Af, Bf[nb][ks],
                                                            C[nb], 0, 0, 0);
    }

    float sums[4] = {0.f, 0.f, 0.f, 0.f};
#pragma unroll
    for (int nb = 0; nb < 4; ++nb) {
#pragma unroll
        for (int reg = 0; reg < 4; ++reg) {
            const int node = node0 + wave * 16 + quad * 4 + reg;
            float u = C[nb][reg] + bias[nb];
            u = (u > 0.f) ? u : 0.f;
            if (node < N_NODES) sums[nb] += u;
        }
        sums[nb] += __shfl_xor(sums[nb], 16);
        sums[nb] += __shfl_xor(sums[nb], 32);
        if (lane < 16) red[wave][nb * 16 + lane] = sums[nb];
    }
    __syncthreads();
    if (tid < 64) {
        partials[blockIdx.x * 64 + tid] =
            red[0][tid] + red[1][tid] + red[2][tid] + red[3][tid];
    }
}

// ---------------------------------------------------------------------------
// Two-stage partials reduction (R9-proven).
// ---------------------------------------------------------------------------
__global__ __launch_bounds__(256) void reduce1_kernel(
    const float* __restrict__ partials, float* __restrict__ part2) {
    __shared__ float red[4][64];
    const int col = threadIdx.x & 63;
    const int seg = threadIdx.x >> 6;
    const int r0 = blockIdx.x * R1_ROWS;
    int r1 = r0 + R1_ROWS;
    if (r1 > N_TILES) r1 = N_TILES;
    float s = 0.f;
    for (int r = r0 + seg; r < r1; r += 4) s += partials[r * 64 + col];
    red[seg][col] = s;
    __syncthreads();
    if (seg == 0) {
        part2[blockIdx.x * 64 + col] =
            red[0][col] + red[1][col] + red[2][col] + red[3][col];
    }
}

__global__ __launch_bounds__(256) void reduce2_kernel(
    const float* __restrict__ part2, float* __restrict__ out) {
    __shared__ float red[4][64];
    const int col = threadIdx.x & 63;
    const int seg = threadIdx.x >> 6;
    float s = 0.f;
    for (int r = seg; r < R1_BLOCKS; r += 4) s += part2[r * 64 + col];
    red[seg][col] = s;
    __syncthreads();
    if (seg == 0) {
        out[col] = red[0][col] + red[1][col] + red[2][col] + red[3][col];
    }
}

extern "C" void kernel_launch(void* const* d_in, const int* in_sizes, int n_in,
                              void* d_out, int out_size, void* d_ws, size_t ws_size,
                              hipStream_t stream) {
    const float* feat = (const float*)d_in[0];
    const float* emb  = (const float*)d_in[1];
    const float* W1   = (const float*)d_in[2];
    const float* b1   = (const float*)d_in[3];
    const float* W2   = (const float*)d_in[4];
    const float* b2   = (const float*)d_in[5];
    const int* edge_src = (const int*)d_in[6];
    const int* edge_dst = (const int*)d_in[7];
    float* out = (float*)d_out;
    char* ws = (char*)d_ws;

    if (ws_size >= (size_t)WS_NEEDED16) {
        // R16 path. bkt aliased into acc16's region (dead once gather8
        // rewrites all of acc16); bcnt aliased into partials.
        int*      cnt      = (int*)ws;
        int*      slots    = (int*)(ws + WS_SLOTS_OFF);
        short*    acc16    = (short*)(ws + WS_ACC16_OFF);
        int*      bkt      = (int*)(ws + WS_ACC16_OFF);
        int*      ovf_cnt  = (int*)(ws + WS_OVFC_OFF);
        int2*     ovf      = (int2*)(ws + WS_OVF_OFF);
        float*    partials = (float*)(ws + WS_PART_OFF);
        int*      bcnt     = (int*)(ws + WS_PART_OFF);
        float*    part2    = (float*)(ws + WS_PART2_OFF);
        unsigned* emb8     = (unsigned*)(ws + WS_EMB8_OFF);

        (void)hipMemsetAsync(ovf_cnt, 0, sizeof(int), stream);
        (void)hipMemsetAsync(bcnt, 0, NB2 * sizeof(int), stream);

        part_kernel<<<P1_BLOCKS + CVT_BLOCKS, 512, 0, stream>>>(
            edge_src, edge_dst, bcnt, bkt, ovf_cnt, ovf, emb, emb8);
        fill2_kernel<<<NB2, 512, 0, stream>>>(bcnt, bkt, cnt, slots,
                                              ovf_cnt, ovf);
        gather8_kernel<<<N_NODES / 4, 256, 0, stream>>>(emb8, cnt, slots, acc16);
        ovf2_kernel<<<1, 64, 0, stream>>>(emb, ovf_cnt, ovf, acc16);

        final_mixed_kernel<<<N_TILES, 256, 0, stream>>>(feat, acc16, W1, b1,
                                                        W2, b2, partials);
        reduce1_kernel<<<R1_BLOCKS, 256, 0, stream>>>(partials, part2);
        reduce2_kernel<<<1, 256, 0, stream>>>(part2, out);
    } else if (ws_size >= (size_t)WS_NEEDED) {
        int*   cnt      = (int*)ws;
        int*   slots    = (int*)(ws + WS_SLOTS_OFF);
        float* acc      = (float*)(ws + WS_ACC_OFF);
        int*   ovf_cnt  = (int*)(ws + WS_OVFC_OFF);
        int2*  ovf      = (int2*)(ws + WS_OVF_OFF);
        float* partials = (float*)(ws + WS_PART_OFF);
        float* part2    = (float*)(ws + WS_PART2_OFF);

        (void)hipMemsetAsync(cnt, 0, N_NODES * sizeof(int), stream);
        (void)hipMemsetAsync(ovf_cnt, 0, sizeof(int), stream);

        fill_kernel<<<NR * N_SLICES, 256, 0, stream>>>(edge_src, edge_dst,
                                                       cnt, slots, ovf_cnt, ovf);
        gather_kernel<<<N_NODES / 4, 256, 0, stream>>>(emb, cnt, slots, acc);
        ovf_kernel<<<16, 256, 0, stream>>>(emb, ovf_cnt, ovf, acc);

        final_kernel<<<N_TILES, 256, 0, stream>>>(feat, acc, W1, b1, W2, b2,
                                                  partials);
        reduce1_kernel<<<R1_BLOCKS, 256, 0, stream>>>(partials, part2);
        reduce2_kernel<<<1, 256, 0, stream>>>(part2, out);
    } else {
        float* acc = (float*)ws;
        (void)hipMemsetAsync(acc, 0, (size_t)N_NODES * D * sizeof(float), stream);
        scatter_kernel<<<(N_EDGES * 64) / 256, 256, 0, stream>>>(emb, edge_src,
                                                                 edge_dst, acc);
        float* partials = (float*)(ws + (size_t)N_NODES * D * sizeof(float));
        float* part2    = partials + (size_t)N_TILES * 64;
        final_kernel<<<N_TILES, 256, 0, stream>>>(feat, acc, W1, b1, W2, b2,
                                                  partials);
        reduce1_kernel<<<R1_BLOCKS, 256, 0, stream>>>(partials, part2);
        reduce2_kernel<<<1, 256, 0, stream>>>(part2, out);
    }
}

// Round 8
// 181.842 us; speedup vs baseline: 1.0868x; 1.0543x over previous
//
#include <hip/hip_runtime.h>

#define N_NODES 100000
#define N_EDGES 1600000
#define D 64
#define CAP 32         // slot cap per node; Poisson(16): P(deg>32)~1e-5/node, ovf backstops
#define OVF_CAP 8192   // overflow edge list (backstop)
#define N_TILES 1563   // (N_NODES + 63) / 64
#define NR 8           // (legacy fill) region groups
#define SLICE_EDGES 2048
#define N_SLICES 782   // ceil(N_EDGES / SLICE_EDGES)
#define R1_BLOCKS 64   // stage-1 reduce blocks
#define R1_ROWS 25     // ceil(N_TILES / R1_BLOCKS)
#define ASTRIDE 136    // final LDS row stride in bf16 elems (128 + 8 pad)

// Bucketed partition (R12-proven) + fused LDS-CSR gather (R17)
#define NB2 782        // buckets of 128 nodes (dst>>7)
#define BCAP2 2560     // per-bucket capacity (mean 2048, sigma~45 -> +11 sigma)
#define EPB 8192       // edges per partition block
#define P1_BLOCKS 196  // ceil(N_EDGES / EPB)
#define CVT_BLOCKS 64  // rider blocks: emb->fp8 ONLY

typedef int    vint4  __attribute__((ext_vector_type(4)));
typedef short  s16x4  __attribute__((ext_vector_type(4)));
typedef short  s16x8  __attribute__((ext_vector_type(8)));
typedef float  f32x2  __attribute__((ext_vector_type(2)));
typedef float  f32x4  __attribute__((ext_vector_type(4)));
typedef __bf16 bf16x8 __attribute__((ext_vector_type(8)));  // MFMA operand type

// f32 -> bf16 (RNE). Inputs are finite; NaN path not needed.
__device__ inline short f2bf(float f) {
    unsigned u = __builtin_bit_cast(unsigned, f);
    u += 0x7fffu + ((u >> 16) & 1u);
    return (short)(u >> 16);
}
__device__ inline s16x4 f2bf4(float4 v) {
    s16x4 r; r.x = f2bf(v.x); r.y = f2bf(v.y); r.z = f2bf(v.z); r.w = f2bf(v.w);
    return r;
}
__device__ inline float bf2f(short s) {
    return __builtin_bit_cast(float, ((unsigned)(unsigned short)s) << 16);
}

// ws layout (bytes), top tier (R17):
//   bkt    @ 0        : NB2*BCAP2 int         (8.0 MB)  [cnt+slots region: dead in top tier]
//   acc16  @ 13201408 : N_NODES*D bf16        (12.8 MB)
//   ovfc   @ 38801408 : int
//   ovf    @ 38801424 : OVF_CAP int2
//   part   @ 38867200 : N_TILES*64 float      (0.4 MB)  [bcnt aliased pre-final]
//   part2  @ 39267328 : R1_BLOCKS*64 float    (16 KB)
//   emb8   @ 39283712 : N_NODES*D bytes       (6.4 MB, OCP e4m3)
#define WS_SLOTS_OFF  401408     // mid-tier CSR slots
#define WS_ACC_OFF    13201408   // mid-tier f32 acc (25.6 MB)
#define WS_ACC16_OFF  13201408
#define WS_OVFC_OFF   38801408
#define WS_OVF_OFF    38801424
#define WS_PART_OFF   38867200
#define WS_PART2_OFF  39267328
#define WS_EMB8_OFF   39283712
#define WS_NEEDED     (WS_PART2_OFF + R1_BLOCKS * 64 * 4)
#define WS_NEEDED16   (WS_EMB8_OFF + N_NODES * D * 2)

// ---------------------------------------------------------------------------
// R12-proven pass 1: edge partition into 782 dst-buckets (128 nodes each).
// Read 8192 edges once -> LDS histogram -> 1024-wide ping-pong scan ->
// LDS-cursor scatter (+bid) -> one global atomicAdd per (block,bucket) ->
// one-thread-per-edge coalesced copy out. pk = (src<<7)|(dst&127).
// Rider blocks (>= P1_BLOCKS): emb -> OCP e4m3 via HW cvt_pk_fp8 only.
// ---------------------------------------------------------------------------
__global__ __launch_bounds__(512) void part_kernel(
    const int* __restrict__ edge_src, const int* __restrict__ edge_dst,
    int* __restrict__ bcnt, int* __restrict__ bkt,
    int* __restrict__ ovf_cnt, int2* __restrict__ ovf,
    const float* __restrict__ emb, unsigned* __restrict__ emb8) {
    const int tid = threadIdx.x;
    if (blockIdx.x >= P1_BLOCKS) {
        const float4* e4 = (const float4*)emb;
        const unsigned t0 = (blockIdx.x - P1_BLOCKS) * 512 + tid;
        for (unsigned j = t0; j < (unsigned)(N_NODES * D / 4);
             j += CVT_BLOCKS * 512) {
            float4 v = e4[j];
            int w = 0;
            w = __builtin_amdgcn_cvt_pk_fp8_f32(v.x, v.y, w, false);
            w = __builtin_amdgcn_cvt_pk_fp8_f32(v.z, v.w, w, true);
            emb8[j] = (unsigned)w;
        }
        return;
    }

    __shared__ int stage[EPB];
    __shared__ unsigned short bid[EPB];
    __shared__ int scA[1024];
    __shared__ int scB[1024];
    __shared__ int hist[NB2];
    int* const cur   = scB;   // dead after scan
    int* const gbase = scA;   // dead after tot/cur captured

    const int e0 = blockIdx.x * EPB;
    for (int i = tid; i < NB2; i += 512) hist[i] = 0;
    __syncthreads();

    int ss[16], dd[16];
#pragma unroll
    for (int i = 0; i < 16; ++i) {
        const int e = e0 + i * 512 + tid;
        if (e < N_EDGES) { ss[i] = edge_src[e]; dd[i] = edge_dst[e]; }
        else             { ss[i] = 0; dd[i] = -1; }
    }

#pragma unroll
    for (int i = 0; i < 16; ++i)
        if (dd[i] >= 0) atomicAdd(&hist[dd[i] >> 7], 1);
    __syncthreads();

    scA[tid]       = (tid < NB2) ? hist[tid] : 0;
    scA[tid + 512] = 0;
    if (tid + 512 < NB2) scA[tid + 512] = hist[tid + 512];
    __syncthreads();
    {
        int* sA = scA;
        int* sB = scB;
        for (int off = 1; off < 1024; off <<= 1) {
            const int i1 = tid + 512;
            const int v0 = sA[tid] + ((tid >= off) ? sA[tid - off] : 0);
            const int v1 = sA[i1] + sA[i1 - off];
            sB[tid] = v0; sB[i1] = v1;
            __syncthreads();
            int* t = sA; sA = sB; sB = t;
        }
    }
    const int tot = scA[NB2 - 1];
    for (int i = tid; i < NB2; i += 512) cur[i] = scA[i] - hist[i];
    __syncthreads();

#pragma unroll
    for (int i = 0; i < 16; ++i) {
        if (dd[i] >= 0) {
            const int b = dd[i] >> 7;
            const int pos = atomicAdd(&cur[b], 1);
            stage[pos] = (ss[i] << 7) | (dd[i] & 127);
            bid[pos] = (unsigned short)b;
        }
    }
    for (int i = tid; i < NB2; i += 512)
        gbase[i] = atomicAdd(&bcnt[i], hist[i]);
    __syncthreads();

    for (int j = tid; j < tot; j += 512) {
        const int pk = stage[j];
        const int b  = bid[j];
        const int gpos = gbase[b] + (j - (cur[b] - hist[b]));
        if (gpos < BCAP2) {
            bkt[b * BCAP2 + gpos] = pk;
        } else {
            int oj = atomicAdd(ovf_cnt, 1);
            if (oj < OVF_CAP) ovf[oj] = make_int2(pk >> 7, (b << 7) | (pk & 127));
        }
    }
}

// ---------------------------------------------------------------------------
// R17 fused fill+gather: block = one 128-node bucket, CSR lives in LDS.
// Phase 1 (fill2-proven pattern): int atomicAdd DIRECTLY on __shared__
// lcnt/lslots (ds-path, fast — R3's disaster was float atomics through a
// generic pointer, never int-on-direct-shared). Phase 2 (gather8-proven
// pattern): per wave, 16 nodes; slots read from LDS; register sums;
// runtime-deg loop (R16's fixed-trip unroll cost ~5us on mean-deg-16 —
// reverted); HW fp8 decode; bf16 store at the producer.
// Kills the fill2 dispatch and the 38.4 MB slots/cnt global round-trip.
// ---------------------------------------------------------------------------
__global__ __launch_bounds__(512) void fillgather_kernel(
    const int* __restrict__ bcnt, const int* __restrict__ bkt,
    const unsigned* __restrict__ emb8,
    int* __restrict__ ovf_cnt, int2* __restrict__ ovf,
    short* __restrict__ acc16) {
    __shared__ int lcnt[128];
    __shared__ int lslots[128 * CAP];   // 16 KB
    const int b = blockIdx.x;
    const int tid = threadIdx.x;
    if (tid < 128) lcnt[tid] = 0;
    __syncthreads();

    // Phase 1: LDS CSR build from the bucket's packed edge run.
    int n = bcnt[b];
    if (n > BCAP2) n = BCAP2;
    for (int i = tid; i < n; i += 512) {
        const int pk = bkt[b * BCAP2 + i];
        const int dl = pk & 127;
        const int pos = atomicAdd(&lcnt[dl], 1);    // int LDS atomic (fast)
        if (pos < CAP) {
            lslots[dl * CAP + pos] = pk >> 7;
        } else {
            int j = atomicAdd(ovf_cnt, 1);
            if (j < OVF_CAP) ovf[j] = make_int2(pk >> 7, (b << 7) | dl);
        }
    }
    __syncthreads();

    // Phase 2: register-sum gather, 16 nodes per wave.
    const int lane = tid & 63;
    const int wave = tid >> 6;
    const int q = lane >> 4;
    const int c = lane & 15;
#pragma unroll 1
    for (int t = 0; t < 16; ++t) {
        const int dl = wave * 16 + t;
        const int v = (b << 7) | dl;
        int deg = lcnt[dl];
        if (deg > CAP) deg = CAP;
        const int si = lslots[dl * CAP + (lane & (CAP - 1))];

        float4 sum = make_float4(0.f, 0.f, 0.f, 0.f);
        for (int e = 0; e < deg; e += 8) {
            const int i0 = e + q, i1 = e + 4 + q;
            const int s0 = __shfl(si, i0 & (CAP - 1));
            const int s1 = __shfl(si, i1 & (CAP - 1));
            unsigned x0 = 0u, x1 = 0u;
            if (i0 < deg) x0 = emb8[(unsigned)s0 * 16 + c];
            if (i1 < deg) x1 = emb8[(unsigned)s1 * 16 + c];
            const f32x2 a0 = __builtin_amdgcn_cvt_pk_f32_fp8((int)x0, false);
            const f32x2 a1 = __builtin_amdgcn_cvt_pk_f32_fp8((int)x0, true);
            const f32x2 b0 = __builtin_amdgcn_cvt_pk_f32_fp8((int)x1, false);
            const f32x2 b1 = __builtin_amdgcn_cvt_pk_f32_fp8((int)x1, true);
            sum.x += a0.x + b0.x;
            sum.y += a0.y + b0.y;
            sum.z += a1.x + b1.x;
            sum.w += a1.y + b1.y;
        }
#pragma unroll
        for (int off = 16; off < 64; off <<= 1) {
            sum.x += __shfl_xor(sum.x, off);
            sum.y += __shfl_xor(sum.y, off);
            sum.z += __shfl_xor(sum.z, off);
            sum.w += __shfl_xor(sum.w, off);
        }
        if (q == 0 && v < N_NODES) {
            *(s16x4*)&acc16[v * D + c * 4] = f2bf4(sum);
        }
    }
}

// Overflow edges: single wave, fully serial over the (tiny) list -> no race
// on the bf16 read-modify-write. lane l owns dim l. (R15-proven.)
__global__ __launch_bounds__(64) void ovf2_kernel(
    const float* __restrict__ emb, const int* __restrict__ ovf_cnt,
    const int2* __restrict__ ovf, short* __restrict__ acc16) {
    int n = *ovf_cnt;
    if (n > OVF_CAP) n = OVF_CAP;
    const int l = threadIdx.x;
    for (int i = 0; i < n; ++i) {
        const int2 e = ovf[i];
        const float a = bf2f(acc16[e.y * D + l]) + emb[e.x * D + l];
        acc16[e.y * D + l] = f2bf(a);
    }
}

// ---------------------------------------------------------------------------
// Legacy region fill + f32 gather + f32 ovf (mid tier / fallback only).
// ---------------------------------------------------------------------------
__global__ __launch_bounds__(256) void fill_kernel(
    const int* __restrict__ edge_src, const int* __restrict__ edge_dst,
    int* __restrict__ cnt, int* __restrict__ slots,
    int* __restrict__ ovf_cnt, int2* __restrict__ ovf) {
    const int r = blockIdx.x & (NR - 1);
    if (r == 7) return;
    const int slice = blockIdx.x >> 3;
    const int base_e = slice * SLICE_EDGES + threadIdx.x * 8;
    if (base_e >= N_EDGES) return;
    const vint4* s4 = (const vint4*)(edge_src + base_e);
    const vint4* d4 = (const vint4*)(edge_dst + base_e);
    vint4 a0 = __builtin_nontemporal_load(s4);
    vint4 a1 = __builtin_nontemporal_load(s4 + 1);
    vint4 b0 = __builtin_nontemporal_load(d4);
    vint4 b1 = __builtin_nontemporal_load(d4 + 1);
    int ss[8] = {a0.x, a0.y, a0.z, a0.w, a1.x, a1.y, a1.z, a1.w};
    int dd[8] = {b0.x, b0.y, b0.z, b0.w, b1.x, b1.y, b1.z, b1.w};
    int pos[8];
#pragma unroll
    for (int i = 0; i < 8; ++i) {
        pos[i] = ((dd[i] >> 14) == r) ? atomicAdd(&cnt[dd[i]], 1) : -1;
    }
#pragma unroll
    for (int i = 0; i < 8; ++i) {
        if (pos[i] >= 0 && pos[i] < CAP) slots[dd[i] * CAP + pos[i]] = ss[i];
    }
#pragma unroll
    for (int i = 0; i < 8; ++i) {
        if (pos[i] >= CAP) {
            int j = atomicAdd(ovf_cnt, 1);
            if (j < OVF_CAP) ovf[j] = make_int2(ss[i], dd[i]);
        }
    }
}

__global__ __launch_bounds__(256) void gather_kernel(
    const float* __restrict__ emb, const int* __restrict__ cnt,
    const int* __restrict__ slots, float* __restrict__ acc) {
    const int lane = threadIdx.x & 63;
    const int wave = threadIdx.x >> 6;
    const int v = blockIdx.x * 4 + wave;
    const int q  = lane >> 4;
    const int c4 = lane & 15;
    int deg = cnt[v];
    if (deg > CAP) deg = CAP;
    const int si = slots[v * CAP + (lane & (CAP - 1))];
    const float4* emb4 = (const float4*)emb;

    float4 sum = make_float4(0.f, 0.f, 0.f, 0.f);
    for (int e = 0; e < deg; e += 4) {
        const int idx = e + q;
        const int s = __shfl(si, idx & (CAP - 1));
        if (idx < deg) {
            float4 a = emb4[s * 16 + c4];
            sum.x += a.x; sum.y += a.y; sum.z += a.z; sum.w += a.w;
        }
    }
#pragma unroll
    for (int off = 16; off < 64; off <<= 1) {
        sum.x += __shfl_xor(sum.x, off);
        sum.y += __shfl_xor(sum.y, off);
        sum.z += __shfl_xor(sum.z, off);
        sum.w += __shfl_xor(sum.w, off);
    }
    if (q == 0) {
        ((float4*)acc)[v * 16 + c4] = sum;
    }
}

__global__ __launch_bounds__(256) void ovf_kernel(
    const float* __restrict__ emb, const int* __restrict__ ovf_cnt,
    const int2* __restrict__ ovf, float* __restrict__ acc) {
    int n = *ovf_cnt;
    if (n > OVF_CAP) n = OVF_CAP;
    const int lane = threadIdx.x & 63;
    const int wv = (blockIdx.x * 256 + threadIdx.x) >> 6;
    const int nwaves = (gridDim.x * 256) >> 6;
    for (int i = wv; i < n; i += nwaves) {
        int2 e = ovf[i];
        unsafeAtomicAdd(&acc[e.y * D + lane], emb[e.x * D + lane]);
    }
}

__global__ __launch_bounds__(256) void scatter_kernel(
    const float* __restrict__ emb,
    const int* __restrict__ edge_src, const int* __restrict__ edge_dst,
    float* __restrict__ acc) {
    int gid = blockIdx.x * 256 + threadIdx.x;
    int e = gid >> 6;
    int c = gid & 63;
    unsafeAtomicAdd(&acc[edge_dst[e] * D + c], emb[edge_src[e] * D + c]);
}

// ---------------------------------------------------------------------------
// R16-proven final: feat f32 (in-kernel cvt) + acc16 bf16 (pure s16x8
// copies) + W f32. MFMA z = [feat|nbr] @ [W1|W2]^T, K=128, 16x16x32,
// 4 k-steps. Fragment layouts m89/m120-verified.
// ---------------------------------------------------------------------------
__global__ __launch_bounds__(256) void final_mixed_kernel(
    const float* __restrict__ feat, const short* __restrict__ acc16,
    const float* __restrict__ W1, const float* __restrict__ b1,
    const float* __restrict__ W2, const float* __restrict__ b2,
    float* __restrict__ partials) {
    __shared__ short A_s[64 * ASTRIDE];
    __shared__ short W_s[64 * ASTRIDE];
    __shared__ float red[4][64];

    const int tid  = threadIdx.x;
    const int lane = tid & 63;
    const int wave = tid >> 6;
    const int quad = lane >> 4;
    const int col  = lane & 15;
    const int node0 = blockIdx.x * 64;

    float bias[4];
#pragma unroll
    for (int nb = 0; nb < 4; ++nb) {
        const int o = nb * 16 + col;
        bias[nb] = b1[o] + b2[o];
    }

    {
        const float4* W1v = (const float4*)W1;
        const float4* W2v = (const float4*)W2;
#pragma unroll
        for (int i = 0; i < 4; ++i) {
            const int flat = tid + i * 256;   // 0..1023
            const int row = flat >> 4, c4 = flat & 15;
            *(s16x4*)&W_s[row * ASTRIDE + c4 * 4]      = f2bf4(W1v[flat]);
            *(s16x4*)&W_s[row * ASTRIDE + 64 + c4 * 4] = f2bf4(W2v[flat]);
        }
    }

    {
        const float4* fv = (const float4*)feat;
#pragma unroll
        for (int i = 0; i < 4; ++i) {
            const int flat = tid + i * 256;
            const int row = flat >> 4, c4 = flat & 15;
            const int node = node0 + row;
            float4 f = make_float4(0.f, 0.f, 0.f, 0.f);
            if (node < N_NODES) f = fv[(size_t)node * 16 + c4];
            *(s16x4*)&A_s[row * ASTRIDE + c4 * 4] = f2bf4(f);
        }
    }
    {
#pragma unroll
        for (int i = 0; i < 2; ++i) {
            const int flat = tid + i * 256;   // 0..511
            const int row = flat >> 3, c = flat & 7;
            const int node = node0 + row;
            s16x8 pk = {0, 0, 0, 0, 0, 0, 0, 0};
            if (node < N_NODES) pk = *(const s16x8*)&acc16[node * D + c * 8];
            *(s16x8*)&A_s[row * ASTRIDE + 64 + c * 8] = pk;
        }
    }
    __syncthreads();

    bf16x8 Bf[4][4];
#pragma unroll
    for (int nb = 0; nb < 4; ++nb)
#pragma unroll
        for (int ks = 0; ks < 4; ++ks)
            Bf[nb][ks] = __builtin_bit_cast(bf16x8,
                *(const s16x8*)&W_s[(nb * 16 + col) * ASTRIDE + ks * 32 + quad * 8]);

    f32x4 C[4];
#pragma unroll
    for (int nb = 0; nb < 4; ++nb) C[nb] = (f32x4){0.f, 0.f, 0.f, 0.f};
#pragma unroll
    for (int ks = 0; ks < 4; ++ks) {
        const bf16x8 Af = __builtin_bit_cast(bf16x8,
            *(const s16x8*)&A_s[(wave * 16 + col) * ASTRIDE + ks * 32 + quad * 8]);
#pragma unroll
        for (int nb = 0; nb < 4; ++nb)
            C[nb] = __builtin_amdgcn_mfma_f32_16x16x32_bf16(Af, Bf[nb][ks],
                                                            C[nb], 0, 0, 0);
    }

    float sums[4] = {0.f, 0.f, 0.f, 0.f};
#pragma unroll
    for (int nb = 0; nb < 4; ++nb) {
#pragma unroll
        for (int reg = 0; reg < 4; ++reg) {
            const int node = node0 + wave * 16 + quad * 4 + reg;
            float u = C[nb][reg] + bias[nb];
            u = (u > 0.f) ? u : 0.f;
            if (node < N_NODES) sums[nb] += u;
        }
        sums[nb] += __shfl_xor(sums[nb], 16);
        sums[nb] += __shfl_xor(sums[nb], 32);
        if (lane < 16) red[wave][nb * 16 + lane] = sums[nb];
    }
    __syncthreads();
    if (tid < 64) {
        partials[blockIdx.x * 64 + tid] =
            red[0][tid] + red[1][tid] + red[2][tid] + red[3][tid];
    }
}

// ---------------------------------------------------------------------------
// Legacy f32-input final (mid tier / fallback).
// ---------------------------------------------------------------------------
__global__ __launch_bounds__(256) void final_kernel(
    const float* __restrict__ feat, const float* __restrict__ acc,
    const float* __restrict__ W1, const float* __restrict__ b1,
    const float* __restrict__ W2, const float* __restrict__ b2,
    float* __restrict__ partials) {
    __shared__ short A_s[64 * ASTRIDE];
    __shared__ short W_s[64 * ASTRIDE];
    __shared__ float red[4][64];

    const int tid  = threadIdx.x;
    const int lane = tid & 63;
    const int wave = tid >> 6;
    const int quad = lane >> 4;
    const int col  = lane & 15;
    const int node0 = blockIdx.x * 64;

    float bias[4];
#pragma unroll
    for (int nb = 0; nb < 4; ++nb) {
        const int o = nb * 16 + col;
        bias[nb] = b1[o] + b2[o];
    }

    {
        const float4* W1v = (const float4*)W1;
        const float4* W2v = (const float4*)W2;
#pragma unroll
        for (int i = 0; i < 4; ++i) {
            const int flat = tid + i * 256;
            const int row = flat >> 4, c4 = flat & 15;
            *(s16x4*)&W_s[row * ASTRIDE + c4 * 4]      = f2bf4(W1v[flat]);
            *(s16x4*)&W_s[row * ASTRIDE + 64 + c4 * 4] = f2bf4(W2v[flat]);
        }
    }

    {
        const float4* fv = (const float4*)feat;
        const float4* av = (const float4*)acc;
#pragma unroll
        for (int i = 0; i < 4; ++i) {
            const int flat = tid + i * 256;
            const int row = flat >> 4, c4 = flat & 15;
            const int node = node0 + row;
            float4 f = make_float4(0.f, 0.f, 0.f, 0.f);
            float4 n = make_float4(0.f, 0.f, 0.f, 0.f);
            if (node < N_NODES) {
                f = fv[(size_t)node * 16 + c4];
                n = av[(size_t)node * 16 + c4];
            }
            *(s16x4*)&A_s[row * ASTRIDE + c4 * 4]      = f2bf4(f);
            *(s16x4*)&A_s[row * ASTRIDE + 64 + c4 * 4] = f2bf4(n);
        }
    }
    __syncthreads();

    bf16x8 Bf[4][4];
#pragma unroll
    for (int nb = 0; nb < 4; ++nb)
#pragma unroll
        for (int ks = 0; ks < 4; ++ks)
            Bf[nb][ks] = __builtin_bit_cast(bf16x8,
                *(const s16x8*)&W_s[(nb * 16 + col) * ASTRIDE + ks * 32 + quad * 8]);

    f32x4 C[4];
#pragma unroll
    for (int nb = 0; nb < 4; ++nb) C[nb] = (f32x4){0.f, 0.f, 0.f, 0.f};
#pragma unroll
    for (int ks = 0; ks < 4; ++ks) {
        const bf16x8 Af = __builtin_bit_cast(bf16x8,
            *(const s16x8*)&A_s[(wave * 16 + col) * ASTRIDE + ks * 32 + quad * 8]);
#pragma unroll
        for (int nb = 0; nb < 4; ++nb)
            C[nb] = __builtin_amdgcn_mfma_f32_16x16x32_bf16(Af, Bf[nb][ks],
                                                            C[nb], 0, 0, 0);
    }

    float sums[4] = {0.f, 0.f, 0.f, 0.f};
#pragma unroll
    for (int nb = 0; nb < 4; ++nb) {
#pragma unroll
        for (int reg = 0; reg < 4; ++reg) {
            const int node = node0 + wave * 16 + quad * 4 + reg;
            float u = C[nb][reg] + bias[nb];
            u = (u > 0.f) ? u : 0.f;
            if (node < N_NODES) sums[nb] += u;
        }
        sums[nb] += __shfl_xor(sums[nb], 16);
        sums[nb] += __shfl_xor(sums[nb], 32);
        if (lane < 16) red[wave][nb * 16 + lane] = sums[nb];
    }
    __syncthreads();
    if (tid < 64) {
        partials[blockIdx.x * 64 + tid] =
            red[0][tid] + red[1][tid] + red[2][tid] + red[3][tid];
    }
}

// ---------------------------------------------------------------------------
// Two-stage partials reduction (R9-proven).
// ---------------------------------------------------------------------------
__global__ __launch_bounds__(256) void reduce1_kernel(
    const float* __restrict__ partials, float* __restrict__ part2) {
    __shared__ float red[4][64];
    const int col = threadIdx.x & 63;
    const int seg = threadIdx.x >> 6;
    const int r0 = blockIdx.x * R1_ROWS;
    int r1 = r0 + R1_ROWS;
    if (r1 > N_TILES) r1 = N_TILES;
    float s = 0.f;
    for (int r = r0 + seg; r < r1; r += 4) s += partials[r * 64 + col];
    red[seg][col] = s;
    __syncthreads();
    if (seg == 0) {
        part2[blockIdx.x * 64 + col] =
            red[0][col] + red[1][col] + red[2][col] + red[3][col];
    }
}

__global__ __launch_bounds__(256) void reduce2_kernel(
    const float* __restrict__ part2, float* __restrict__ out) {
    __shared__ float red[4][64];
    const int col = threadIdx.x & 63;
    const int seg = threadIdx.x >> 6;
    float s = 0.f;
    for (int r = seg; r < R1_BLOCKS; r += 4) s += part2[r * 64 + col];
    red[seg][col] = s;
    __syncthreads();
    if (seg == 0) {
        out[col] = red[0][col] + red[1][col] + red[2][col] + red[3][col];
    }
}

extern "C" void kernel_launch(void* const* d_in, const int* in_sizes, int n_in,
                              void* d_out, int out_size, void* d_ws, size_t ws_size,
                              hipStream_t stream) {
    const float* feat = (const float*)d_in[0];
    const float* emb  = (const float*)d_in[1];
    const float* W1   = (const float*)d_in[2];
    const float* b1   = (const float*)d_in[3];
    const float* W2   = (const float*)d_in[4];
    const float* b2   = (const float*)d_in[5];
    const int* edge_src = (const int*)d_in[6];
    const int* edge_dst = (const int*)d_in[7];
    float* out = (float*)d_out;
    char* ws = (char*)d_ws;

    if (ws_size >= (size_t)WS_NEEDED16) {
        // R17 path. bkt now lives at offset 0 (old cnt+slots region — dead in
        // this tier) so it does NOT alias acc16 (fillgather reads bkt while
        // writing acc16). bcnt aliased into partials (dead until final).
        int*      bkt      = (int*)ws;
        short*    acc16    = (short*)(ws + WS_ACC16_OFF);
        int*      ovf_cnt  = (int*)(ws + WS_OVFC_OFF);
        int2*     ovf      = (int2*)(ws + WS_OVF_OFF);
        float*    partials = (float*)(ws + WS_PART_OFF);
        int*      bcnt     = (int*)(ws + WS_PART_OFF);
        float*    part2    = (float*)(ws + WS_PART2_OFF);
        unsigned* emb8     = (unsigned*)(ws + WS_EMB8_OFF);

        (void)hipMemsetAsync(ovf_cnt, 0, sizeof(int), stream);
        (void)hipMemsetAsync(bcnt, 0, NB2 * sizeof(int), stream);

        part_kernel<<<P1_BLOCKS + CVT_BLOCKS, 512, 0, stream>>>(
            edge_src, edge_dst, bcnt, bkt, ovf_cnt, ovf, emb, emb8);
        fillgather_kernel<<<NB2, 512, 0, stream>>>(bcnt, bkt, emb8,
                                                   ovf_cnt, ovf, acc16);
        ovf2_kernel<<<1, 64, 0, stream>>>(emb, ovf_cnt, ovf, acc16);

        final_mixed_kernel<<<N_TILES, 256, 0, stream>>>(feat, acc16, W1, b1,
                                                        W2, b2, partials);
        reduce1_kernel<<<R1_BLOCKS, 256, 0, stream>>>(partials, part2);
        reduce2_kernel<<<1, 256, 0, stream>>>(part2, out);
    } else if (ws_size >= (size_t)WS_NEEDED) {
        int*   cnt      = (int*)ws;
        int*   slots    = (int*)(ws + WS_SLOTS_OFF);
        float* acc      = (float*)(ws + WS_ACC_OFF);
        int*   ovf_cnt  = (int*)(ws + WS_OVFC_OFF);
        int2*  ovf      = (int2*)(ws + WS_OVF_OFF);
        float* partials = (float*)(ws + WS_PART_OFF);
        float* part2    = (float*)(ws + WS_PART2_OFF);

        (void)hipMemsetAsync(cnt, 0, N_NODES * sizeof(int), stream);
        (void)hipMemsetAsync(ovf_cnt, 0, sizeof(int), stream);

        fill_kernel<<<NR * N_SLICES, 256, 0, stream>>>(edge_src, edge_dst,
                                                       cnt, slots, ovf_cnt, ovf);
        gather_kernel<<<N_NODES / 4, 256, 0, stream>>>(emb, cnt, slots, acc);
        ovf_kernel<<<16, 256, 0, stream>>>(emb, ovf_cnt, ovf, acc);

        final_kernel<<<N_TILES, 256, 0, stream>>>(feat, acc, W1, b1, W2, b2,
                                                  partials);
        reduce1_kernel<<<R1_BLOCKS, 256, 0, stream>>>(partials, part2);
        reduce2_kernel<<<1, 256, 0, stream>>>(part2, out);
    } else {
        float* acc = (float*)ws;
        (void)hipMemsetAsync(acc, 0, (size_t)N_NODES * D * sizeof(float), stream);
        scatter_kernel<<<(N_EDGES * 64) / 256, 256, 0, stream>>>(emb, edge_src,
                                                                 edge_dst, acc);
        float* partials = (float*)(ws + (size_t)N_NODES * D * sizeof(float));
        float* part2    = partials + (size_t)N_TILES * 64;
        final_kernel<<<N_TILES, 256, 0, stream>>>(feat, acc, W1, b1, W2, b2,
                                                  partials);
        reduce1_kernel<<<R1_BLOCKS, 256, 0, stream>>>(partials, part2);
        reduce2_kernel<<<1, 256, 0, stream>>>(part2, out);
    }
}